// Round 5
// baseline (444.808 us; speedup 1.0000x reference)
//
#include <hip/hip_runtime.h>

#define HID 32
#define SEQ 512
#define GROUPS_PER_BLOCK 8
#define BLOCK (GROUPS_PER_BLOCK * 32)

typedef float v2f __attribute__((ext_vector_type(2)));

__device__ __forceinline__ float fast_exp(float x) {
    return __builtin_amdgcn_exp2f(x * 1.44269504088896340736f);
}
__device__ __forceinline__ float fast_rcp(float x) {
    return __builtin_amdgcn_rcpf(x);
}
__device__ __forceinline__ float sigmoid_f(float x) {
    return fast_rcp(1.0f + fast_exp(-x));
}
__device__ __forceinline__ float tanh_f(float x) {
    return 1.0f - 2.0f * fast_rcp(1.0f + fast_exp(2.0f * x));
}

// Broadcast lane J (0..31) within each 32-lane half of the wave.
// ds_swizzle BitMode imm: offset = (xor<<10)|(or<<5)|and; or=J, and=0 -> lane J.
#define BCAST32(v, J) \
    __int_as_float(__builtin_amdgcn_ds_swizzle(__float_as_int(v), ((J) << 5)))

__global__ __launch_bounds__(BLOCK)
__attribute__((amdgpu_waves_per_eu(1, 2)))
void lstm_fused_kernel(
    const float* __restrict__ x,       // [B, T, 1]
    const float* __restrict__ W_ih,    // [4H, 1]
    const float* __restrict__ W_hh,    // [4H, H] row-major
    const float* __restrict__ b_ih,    // [4H]
    const float* __restrict__ b_hh,    // [4H]
    const float* __restrict__ W_head,  // [1, H]
    const float* __restrict__ b_head,  // [1]
    float* __restrict__ out)           // [B, 1]
{
    // Weight pairs stored CONTIGUOUSLY so each fragment is one ds_read_b64:
    // WifL[j*32 + k] = (W_hh[i-gate row k][j], W_hh[f-gate row 32+k][j])
    // WgoL[j*32 + k] = (W_hh[g-gate row 64+k][j], W_hh[o-gate row 96+k][j])
    __shared__ v2f WifL[32 * 32];
    __shared__ v2f WgoL[32 * 32];
    const int tid = threadIdx.x;
    for (int idx = tid; idx < 1024; idx += BLOCK) {
        const int j  = idx >> 5;   // hidden col 0..31
        const int kk = idx & 31;   // unit 0..31
        WifL[idx] = (v2f){ W_hh[kk * 32 + j],        W_hh[(32 + kk) * 32 + j] };
        WgoL[idx] = (v2f){ W_hh[(64 + kk) * 32 + j], W_hh[(96 + kk) * 32 + j] };
    }
    __syncthreads();

    const int k   = tid & 31;   // hidden unit owned by this lane
    const int grp = tid >> 5;   // batch group within block (0..7)
    const int b   = blockIdx.x * GROUPS_PER_BLOCK + grp;

    // --- Load all 64 weight pairs via VOLATILE asm ds_read_b64. ---
    // A volatile asm result cannot be rematerialized: this forbids the
    // compiler's in-loop LDS re-read strategy (rounds 0-4 were DS-issue-bound
    // on ~128 weight re-reads per timestep; wall/CU-step 1550cy == 8 waves x
    // ~160 DS ops, VALUBusy 60% == 940/1550 -- both match).
    // Each load carries its own waitcnt: one-time ~120cy x 64 = ~3us, and no
    // hazard from compiler reordering around untracked asm DS ops.
    // Address register auto-increments by 256B (= 32 pairs) per load.
    v2f w_if[HID], w_go[HID];
    unsigned a_if = (unsigned)(size_t)(&WifL[k]);
    unsigned a_go = (unsigned)(size_t)(&WgoL[k]);
#define LDIF(J) asm volatile( \
        "ds_read_b64 %0, %1\n\t" \
        "s_waitcnt lgkmcnt(0)\n\t" \
        "v_add_u32 %1, 256, %1" \
        : "=v"(w_if[J]), "+v"(a_if));
#define LDGO(J) asm volatile( \
        "ds_read_b64 %0, %1\n\t" \
        "s_waitcnt lgkmcnt(0)\n\t" \
        "v_add_u32 %1, 256, %1" \
        : "=v"(w_go[J]), "+v"(a_go));
    LDIF(0)  LDIF(1)  LDIF(2)  LDIF(3)  LDIF(4)  LDIF(5)  LDIF(6)  LDIF(7)
    LDIF(8)  LDIF(9)  LDIF(10) LDIF(11) LDIF(12) LDIF(13) LDIF(14) LDIF(15)
    LDIF(16) LDIF(17) LDIF(18) LDIF(19) LDIF(20) LDIF(21) LDIF(22) LDIF(23)
    LDIF(24) LDIF(25) LDIF(26) LDIF(27) LDIF(28) LDIF(29) LDIF(30) LDIF(31)
    LDGO(0)  LDGO(1)  LDGO(2)  LDGO(3)  LDGO(4)  LDGO(5)  LDGO(6)  LDGO(7)
    LDGO(8)  LDGO(9)  LDGO(10) LDGO(11) LDGO(12) LDGO(13) LDGO(14) LDGO(15)
    LDGO(16) LDGO(17) LDGO(18) LDGO(19) LDGO(20) LDGO(21) LDGO(22) LDGO(23)
    LDGO(24) LDGO(25) LDGO(26) LDGO(27) LDGO(28) LDGO(29) LDGO(30) LDGO(31)
#undef LDIF
#undef LDGO

    const v2f bv_if = { b_ih[k]      + b_hh[k],      b_ih[32 + k] + b_hh[32 + k] };
    const v2f bv_go = { b_ih[64 + k] + b_hh[64 + k], b_ih[96 + k] + b_hh[96 + k] };
    const v2f uv_if = { W_ih[k],      W_ih[32 + k] };
    const v2f uv_go = { W_ih[64 + k], W_ih[96 + k] };

    const float* xb = x + (size_t)b * SEQ;  // I == 1, so x[b][t][0] = xb[t]

    float h = 0.0f, c = 0.0f;

    // JS2(M): gate FMAs for j = 2M and 2M+1 (validated in round 4).
    // hv = (h[2M], h[2M+1]) from two immediate ds_swizzle broadcasts;
    // v_pk_fma_f32 op_sel splats one half of hv across both gate lanes:
    //   op_sel_hi:[1,0,1]                -> multiply by hv.lo (= h[2M])
    //   op_sel:[0,1,0] op_sel_hi:[1,1,1] -> multiply by hv.hi (= h[2M+1])
    // Per-gate fma order is j ascending -> bitwise-identical numerics.
#define JS2(M) { \
        const v2f hv = { BCAST32(h, 2*(M)), BCAST32(h, 2*(M)+1) }; \
        asm("v_pk_fma_f32 %0, %2, %4, %0 op_sel_hi:[1,0,1]\n\t" \
            "v_pk_fma_f32 %1, %3, %4, %1 op_sel_hi:[1,0,1]\n\t" \
            "v_pk_fma_f32 %0, %5, %4, %0 op_sel:[0,1,0] op_sel_hi:[1,1,1]\n\t" \
            "v_pk_fma_f32 %1, %6, %4, %1 op_sel:[0,1,0] op_sel_hi:[1,1,1]" \
            : "+v"(aif), "+v"(ago) \
            : "v"(w_if[2*(M)]), "v"(w_go[2*(M)]), "v"(hv), \
              "v"(w_if[2*(M)+1]), "v"(w_go[2*(M)+1])); \
    }

    for (int t0 = 0; t0 < SEQ; t0 += 32) {
        // lane k prefetches x[b][t0+k]; broadcast per-step via shuffle
        const float xv = xb[t0 + k];
#pragma unroll 4
        for (int tt = 0; tt < 32; ++tt) {
            const float xt = __shfl(xv, tt, 32);
            const v2f xtv = { xt, xt };
            v2f aif = __builtin_elementwise_fma(xtv, uv_if, bv_if);
            v2f ago = __builtin_elementwise_fma(xtv, uv_go, bv_go);
            JS2(0)  JS2(1)  JS2(2)  JS2(3)
            JS2(4)  JS2(5)  JS2(6)  JS2(7)
            JS2(8)  JS2(9)  JS2(10) JS2(11)
            JS2(12) JS2(13) JS2(14) JS2(15)
            const float ig = sigmoid_f(aif.x);
            const float fg = sigmoid_f(aif.y);
            const float gg = tanh_f(ago.x);
            const float og = sigmoid_f(ago.y);
            c = __builtin_fmaf(fg, c, ig * gg);
            h = og * tanh_f(c);
        }
    }
#undef JS2

    // head: out[b] = sum_k h[k] * W_head[0][k] + b_head[0]
    float v = h * W_head[k];
#pragma unroll
    for (int off = 16; off >= 1; off >>= 1)
        v += __shfl_xor(v, off, 32);
    if (k == 0) out[b] = v + b_head[0];
}

extern "C" void kernel_launch(void* const* d_in, const int* in_sizes, int n_in,
                              void* d_out, int out_size, void* d_ws, size_t ws_size,
                              hipStream_t stream) {
    const float* x      = (const float*)d_in[0];
    const float* W_ih   = (const float*)d_in[1];
    const float* W_hh   = (const float*)d_in[2];
    const float* b_ih   = (const float*)d_in[3];
    const float* b_hh   = (const float*)d_in[4];
    const float* W_head = (const float*)d_in[5];
    const float* b_head = (const float*)d_in[6];
    float* out = (float*)d_out;

    const int B = in_sizes[0] / SEQ;          // 4096
    const int grid = B / GROUPS_PER_BLOCK;    // 512 blocks

    lstm_fused_kernel<<<grid, BLOCK, 0, stream>>>(
        x, W_ih, W_hh, b_ih, b_hh, W_head, b_head, out);
}

// Round 6
// 389.168 us; speedup vs baseline: 1.1430x; 1.1430x over previous
//
#include <hip/hip_runtime.h>

#define HID 32
#define SEQ 512
#define WAVES_PER_BLOCK 4
#define BLOCK (WAVES_PER_BLOCK * 64)

typedef float v2f __attribute__((ext_vector_type(2)));

__device__ __forceinline__ float fast_exp(float x) {
    return __builtin_amdgcn_exp2f(x * 1.44269504088896340736f);
}
__device__ __forceinline__ float fast_rcp(float x) {
    return __builtin_amdgcn_rcpf(x);
}
__device__ __forceinline__ float sigmoid_f(float x) {
    return fast_rcp(1.0f + fast_exp(-x));
}
__device__ __forceinline__ float tanh_f(float x) {
    return 1.0f - 2.0f * fast_rcp(1.0f + fast_exp(2.0f * x));
}

// ONE WAVE = ONE BATCH SAMPLE.
// lane = (half, k): half 0 owns gates (i,f) of unit k, half 1 owns (g,o).
// -> only 32 v2f (64 floats) of W_hh per lane. Rounds 1-5 proved the RA
// will not architecturally host 128 floats/lane (it AGPR-parks them and
// pays ~128 v_accvgpr_read per step: measured 225 instr/step vs 97 ideal,
// across every coercion attempt). 64 floats fits the ~100-reg budget the
// RA actually gives, so the pk_fma asm reads weights copy-free.
__global__ __launch_bounds__(BLOCK)
void lstm_fused_kernel(
    const float* __restrict__ x,       // [B, T, 1]
    const float* __restrict__ W_ih,    // [4H, 1]
    const float* __restrict__ W_hh,    // [4H, H] row-major
    const float* __restrict__ b_ih,    // [4H]
    const float* __restrict__ b_hh,    // [4H]
    const float* __restrict__ W_head,  // [1, H]
    const float* __restrict__ b_head,  // [1]
    float* __restrict__ out)           // [B, 1]
{
    // WL[j*64 + lane] = (W_hh[rowA][j], W_hh[rowA+32][j]) where
    // rowA = half*64 + k  (half0: i-row k / f-row 32+k; half1: g / o).
    __shared__ v2f WL[32 * 64];                         // 16 KB
    __shared__ __align__(16) float Hbuf[WAVES_PER_BLOCK][32];

    const int tid = threadIdx.x;
    for (int idx = tid; idx < 32 * 64; idx += BLOCK) {
        const int j    = idx >> 6;    // hidden col 0..31
        const int l    = idx & 63;
        const int rowA = ((l >> 5) << 6) + (l & 31);    // half*64 + k
        WL[idx] = (v2f){ W_hh[rowA * 32 + j], W_hh[(rowA + 32) * 32 + j] };
    }
    __syncthreads();

    const int  lane = tid & 63;
    const int  k    = lane & 31;
    const bool hi   = lane >= 32;
    const int  wid  = tid >> 6;
    const int  b    = blockIdx.x * WAVES_PER_BLOCK + wid;

    // Load the 32 weight pairs via VOLATILE asm ds_read_b64 (cannot be
    // rematerialized in-loop; mechanism validated correct in round 5).
    // Address auto-increments 512 B (= 64 pairs) per j.
    v2f w[HID];
    unsigned a_w = (unsigned)(size_t)(&WL[lane]);
#define LDW(J) asm volatile( \
        "ds_read_b64 %0, %1\n\t" \
        "s_waitcnt lgkmcnt(0)\n\t" \
        "v_add_u32 %1, 512, %1" \
        : "=v"(w[J]), "+v"(a_w));
    LDW(0)  LDW(1)  LDW(2)  LDW(3)  LDW(4)  LDW(5)  LDW(6)  LDW(7)
    LDW(8)  LDW(9)  LDW(10) LDW(11) LDW(12) LDW(13) LDW(14) LDW(15)
    LDW(16) LDW(17) LDW(18) LDW(19) LDW(20) LDW(21) LDW(22) LDW(23)
    LDW(24) LDW(25) LDW(26) LDW(27) LDW(28) LDW(29) LDW(30) LDW(31)
#undef LDW

    const int gA = (hi ? 64 : 0) + k;   // i-row or g-row
    const int gB = gA + 32;             // f-row or o-row
    const v2f bv = { b_ih[gA] + b_hh[gA], b_ih[gB] + b_hh[gB] };
    const v2f uv = { W_ih[gA], W_ih[gB] };

    float* Hrow = &Hbuf[wid][0];
    const float* xb = x + (size_t)b * SEQ;   // I == 1

    float h = 0.0f, c = 0.0f;
    Hrow[k] = 0.0f;   // both halves write the same value: benign
    asm volatile("" ::: "memory");

    // JS2(M): acc += w[2M]*h[2M] + w[2M+1]*h[2M+1] via two v_pk_fma_f32.
    // hp[M] = (h[2M], h[2M+1]); op_sel splats one half across both gates:
    //   op_sel_hi:[1,0,1]                -> multiply by hp.lo (= h[2M])
    //   op_sel:[0,1,0] op_sel_hi:[1,1,1] -> multiply by hp.hi (= h[2M+1])
    // j ascending -> per-gate chain bitwise-identical to reference.
#define JS2(M) { \
        asm("v_pk_fma_f32 %0, %2, %1, %0 op_sel_hi:[1,0,1]\n\t" \
            "v_pk_fma_f32 %0, %3, %1, %0 op_sel:[0,1,0] op_sel_hi:[1,1,1]" \
            : "+v"(acc) \
            : "v"(hp[M]), "v"(w[2*(M)]), "v"(w[2*(M)+1])); \
    }

    for (int t0 = 0; t0 < SEQ; t0 += 32) {
        const float xv = xb[t0 + k];   // halves load identical words (coalesced)
#pragma unroll 4
        for (int tt = 0; tt < 32; ++tt) {
            // Read h (written last step) as 16 v2f pairs; uniform addresses
            // broadcast conflict-free, compiler merges into b64/read2.
            v2f hp[16];
#pragma unroll
            for (int m = 0; m < 16; ++m)
                hp[m] = *(const v2f*)(Hrow + 2 * m);

            const float xt = __shfl(xv, tt, 32);
            const v2f xtv = { xt, xt };
            v2f acc = __builtin_elementwise_fma(xtv, uv, bv);
            JS2(0)  JS2(1)  JS2(2)  JS2(3)
            JS2(4)  JS2(5)  JS2(6)  JS2(7)
            JS2(8)  JS2(9)  JS2(10) JS2(11)
            JS2(12) JS2(13) JS2(14) JS2(15)

            // Exchange gate pairs across halves: half0 has (pi,pf),
            // half1 has (pg,po); after this every lane has all four.
            const float qx = __shfl_xor(acc.x, 32);
            const float qy = __shfl_xor(acc.y, 32);
            const float pi = hi ? qx : acc.x;
            const float pf = hi ? qy : acc.y;
            const float pg = hi ? acc.x : qx;
            const float po = hi ? acc.y : qy;

            const float ig = sigmoid_f(pi);
            const float fg = sigmoid_f(pf);
            const float gg = tanh_f(pg);
            const float og = sigmoid_f(po);
            c = __builtin_fmaf(fg, c, ig * gg);
            h = og * tanh_f(c);

            Hrow[k] = h;   // both halves store identical value
            asm volatile("" ::: "memory");   // forbid hoisting next step's
                                             // hp loads above this store
        }
    }
#undef JS2

    // head: out[b] = sum_k h[k] * W_head[0][k] + b_head[0]
    float v = h * W_head[k];
#pragma unroll
    for (int off = 16; off >= 1; off >>= 1)
        v += __shfl_xor(v, off, 32);
    if (lane == 0) out[b] = v + b_head[0];
}

extern "C" void kernel_launch(void* const* d_in, const int* in_sizes, int n_in,
                              void* d_out, int out_size, void* d_ws, size_t ws_size,
                              hipStream_t stream) {
    const float* x      = (const float*)d_in[0];
    const float* W_ih   = (const float*)d_in[1];
    const float* W_hh   = (const float*)d_in[2];
    const float* b_ih   = (const float*)d_in[3];
    const float* b_hh   = (const float*)d_in[4];
    const float* W_head = (const float*)d_in[5];
    const float* b_head = (const float*)d_in[6];
    float* out = (float*)d_out;

    const int B = in_sizes[0] / SEQ;              // 4096
    const int grid = B / WAVES_PER_BLOCK;         // 1024 blocks (4 waves each)

    lstm_fused_kernel<<<grid, BLOCK, 0, stream>>>(
        x, W_ih, W_hh, b_ih, b_hh, W_head, b_head, out);
}

// Round 7
// 341.928 us; speedup vs baseline: 1.3009x; 1.1382x over previous
//
#include <hip/hip_runtime.h>

#define HID 32
#define SEQ 512
#define WAVES_PER_BLOCK 4
#define BLOCK (WAVES_PER_BLOCK * 64)

typedef float v2f __attribute__((ext_vector_type(2)));

// ---------------------------------------------------------------------------
// ONE WAVE = ONE BATCH SAMPLE; the whole 32-timestep inner loop is a single
// asm block. Rationale (rounds 1-6): any per-step asm/intrinsic site that
// consumes long-lived C values pays AGPR<->VGPR copies at every site
// (measured ~171 VALU instr/wave-step vs ~66 ideal, across six allocator-
// coercion attempts). Binding the weights ONCE per 32 steps amortizes any
// parking to <=64 copies / 32 steps. Hard-coded scratch v80-v108 (clobbered)
// gives sub-register control (pair halves, b128 quads) the operand syntax
// can't express.
//
// Lane roles: lane = (half, k). half0 owns gates (i,f) of unit k, half1 owns
// (g,o).  LDS row per wave (128 floats): [0:32)=h, [32:64)=x chunk,
// [64:96)=dump (half1's garbage h).  Split activation: x-component is
// sigma or tanh via per-lane exp-scale + affine A+B*r (uniform code, no
// divergence); y-component is sigma for both halves. One-way bpermute
// (lane^32) hands half1's (tanh(pg), sigma(po)) to half0; half1 computes
// garbage c/h into the dump slot. All per-gate fma chains and activation
// formulas are bitwise-identical to round 6 (which passed with absmax 0).
// ---------------------------------------------------------------------------

// acc += wE*h_even + wO*h_odd via validated op_sel forms (rounds 4-6):
//   op_sel_hi:[1,0,1]                -> both halves multiply by S1.lo
//   op_sel:[0,1,0] op_sel_hi:[1,1,1] -> both halves multiply by S1.hi
#define PK2(WE, WO, R) \
  "v_pk_fma_f32 v[80:81], %[" WE "], " R ", v[80:81] op_sel_hi:[1,0,1]\n\t" \
  "v_pk_fma_f32 v[80:81], %[" WO "], " R ", v[80:81] op_sel:[0,1,0] op_sel_hi:[1,1,1]\n\t"

// One timestep. Scratch map: v[80:81]=acc, v[82:83]=(xt,xt),
// v[84:99]=four h-quads (streamed), v100-v107 activation temps, v108=x addr.
// h-quad reads are uniform-address (broadcast, conflict-free); counted
// lgkmcnt keeps 3-4 reads in flight (extra prior DS ops from C only make
// waits stricter, never looser).
#define STEPSTR \
  "ds_read2_b32 v[82:83], v108 offset0:0 offset1:0\n\t" \
  "ds_read_b128 v[84:87], %[vRD] offset:0\n\t" \
  "ds_read_b128 v[88:91], %[vRD] offset:16\n\t" \
  "ds_read_b128 v[92:95], %[vRD] offset:32\n\t" \
  "ds_read_b128 v[96:99], %[vRD] offset:48\n\t" \
  "v_add_u32 v108, 4, v108\n\t" \
  "s_waitcnt lgkmcnt(4)\n\t" \
  "v_pk_fma_f32 v[80:81], %[uv], v[82:83], %[bv]\n\t" \
  "s_waitcnt lgkmcnt(3)\n\t" \
  PK2("w0","w1","v[84:85]") \
  PK2("w2","w3","v[86:87]") \
  "ds_read_b128 v[84:87], %[vRD] offset:64\n\t" \
  "s_waitcnt lgkmcnt(3)\n\t" \
  PK2("w4","w5","v[88:89]") \
  PK2("w6","w7","v[90:91]") \
  "ds_read_b128 v[88:91], %[vRD] offset:80\n\t" \
  "s_waitcnt lgkmcnt(3)\n\t" \
  PK2("w8","w9","v[92:93]") \
  PK2("w10","w11","v[94:95]") \
  "ds_read_b128 v[92:95], %[vRD] offset:96\n\t" \
  "s_waitcnt lgkmcnt(3)\n\t" \
  PK2("w12","w13","v[96:97]") \
  PK2("w14","w15","v[98:99]") \
  "ds_read_b128 v[96:99], %[vRD] offset:112\n\t" \
  "s_waitcnt lgkmcnt(3)\n\t" \
  PK2("w16","w17","v[84:85]") \
  PK2("w18","w19","v[86:87]") \
  "s_waitcnt lgkmcnt(2)\n\t" \
  PK2("w20","w21","v[88:89]") \
  PK2("w22","w23","v[90:91]") \
  "s_waitcnt lgkmcnt(1)\n\t" \
  PK2("w24","w25","v[92:93]") \
  PK2("w26","w27","v[94:95]") \
  "s_waitcnt lgkmcnt(0)\n\t" \
  PK2("w28","w29","v[96:97]") \
  PK2("w30","w31","v[98:99]") \
  "v_mul_f32 v100, %[vSX], v80\n\t" \
  "v_mul_f32 v103, 0xbfb8aa3b, v81\n\t" \
  "v_exp_f32 v100, v100\n\t" \
  "v_exp_f32 v103, v103\n\t" \
  "s_nop 1\n\t" \
  "v_add_f32 v100, 1.0, v100\n\t" \
  "v_add_f32 v103, 1.0, v103\n\t" \
  "v_rcp_f32 v101, v100\n\t" \
  "v_rcp_f32 v103, v103\n\t" \
  "s_nop 1\n\t" \
  "v_fma_f32 v102, %[vB], v101, %[vA]\n\t" \
  "ds_bpermute_b32 v104, %[vXOR], v102\n\t" \
  "ds_bpermute_b32 v105, %[vXOR], v103\n\t" \
  "s_waitcnt lgkmcnt(0)\n\t" \
  "v_mul_f32 v106, v102, v104\n\t" \
  "v_fma_f32 %[c], v103, %[c], v106\n\t" \
  "v_mul_f32 v107, 0x4038aa3b, %[c]\n\t" \
  "v_exp_f32 v107, v107\n\t" \
  "s_nop 1\n\t" \
  "v_add_f32 v107, 1.0, v107\n\t" \
  "v_rcp_f32 v107, v107\n\t" \
  "s_nop 1\n\t" \
  "v_fma_f32 v107, -2.0, v107, 1.0\n\t" \
  "v_mul_f32 %[h], v105, v107\n\t" \
  "ds_write_b32 %[vWR], %[h]\n\t"

#define S4  STEPSTR STEPSTR STEPSTR STEPSTR
#define X32 S4 S4 S4 S4 S4 S4 S4 S4

__global__ __launch_bounds__(BLOCK)
void lstm_fused_kernel(
    const float* __restrict__ x,       // [B, T, 1]
    const float* __restrict__ W_ih,    // [4H, 1]
    const float* __restrict__ W_hh,    // [4H, H] row-major
    const float* __restrict__ b_ih,    // [4H]
    const float* __restrict__ b_hh,    // [4H]
    const float* __restrict__ W_head,  // [1, H]
    const float* __restrict__ b_head,  // [1]
    float* __restrict__ out)           // [B, 1]
{
    // WL[j*64 + lane] = (W_hh[rowA][j], W_hh[rowA+32][j]),
    // rowA = half*64 + k  (half0: i/f rows; half1: g/o rows).
    __shared__ v2f WL[32 * 64];                                  // 16 KB
    __shared__ __align__(64) float Hbuf[WAVES_PER_BLOCK][128];   //  2 KB

    const int tid = threadIdx.x;
    for (int idx = tid; idx < 32 * 64; idx += BLOCK) {
        const int j    = idx >> 6;
        const int l    = idx & 63;
        const int rowA = ((l >> 5) << 6) + (l & 31);
        WL[idx] = (v2f){ W_hh[rowA * 32 + j], W_hh[(rowA + 32) * 32 + j] };
    }
    __syncthreads();

    const int  lane = tid & 63;
    const int  k    = lane & 31;
    const bool hi   = lane >= 32;
    const int  wid  = tid >> 6;
    const int  b    = blockIdx.x * WAVES_PER_BLOCK + wid;

    // 32 weight pairs per lane; bound once per asm entry below.
    v2f w[HID];
#pragma unroll
    for (int j = 0; j < HID; ++j) w[j] = WL[j * 64 + lane];

    const int gA = (hi ? 64 : 0) + k;   // i-row (half0) or g-row (half1)
    const int gB = gA + 32;             // f-row or o-row
    const v2f bv = { b_ih[gA] + b_hh[gA], b_ih[gB] + b_hh[gB] };
    const v2f uv = { W_ih[gA], W_ih[gB] };

    float* Hrow = &Hbuf[wid][0];
    const unsigned vRD  = (unsigned)(size_t)Hrow;                  // row base
    const unsigned vWR  = vRD + (hi ? 256u : 0u) + (unsigned)(k * 4); // h or dump
    const unsigned vXOR = (unsigned)(((lane ^ 32) & 63) * 4);      // bpermute addr
    // x-activation: e = exp2(sX*p); r = rcp(1+e); result = B*r + A.
    // half0: sigma  (sX=-log2e, A=0, B=1)   -> fma(1,r,0)==r bitwise.
    // half1: tanh   (sX=+2log2e, A=1, B=-2) -> 1-2r, same as round 6.
    const float vSX = hi ?  2.8853900817779268f : -1.4426950408889634f;
    const float vA  = hi ?  1.0f :  0.0f;
    const float vB  = hi ? -2.0f :  1.0f;

    const float* xb = x + (size_t)b * SEQ;   // I == 1

    Hrow[k] = 0.0f;          // h(0); both halves write same value (benign)
    float h = 0.0f, c = 0.0f;

#pragma unroll 1
    for (int t0 = 0; t0 < SEQ; t0 += 32) {
        Hrow[32 + k] = xb[t0 + k];   // x chunk (halves write identical words)
        asm volatile(
            "v_add_u32 v108, 128, %[vRD]\n\t"   // x slot byte addr
            X32
            : [h]"+v"(h), [c]"+v"(c)
            : [w0]"v"(w[0]),  [w1]"v"(w[1]),  [w2]"v"(w[2]),  [w3]"v"(w[3]),
              [w4]"v"(w[4]),  [w5]"v"(w[5]),  [w6]"v"(w[6]),  [w7]"v"(w[7]),
              [w8]"v"(w[8]),  [w9]"v"(w[9]),  [w10]"v"(w[10]),[w11]"v"(w[11]),
              [w12]"v"(w[12]),[w13]"v"(w[13]),[w14]"v"(w[14]),[w15]"v"(w[15]),
              [w16]"v"(w[16]),[w17]"v"(w[17]),[w18]"v"(w[18]),[w19]"v"(w[19]),
              [w20]"v"(w[20]),[w21]"v"(w[21]),[w22]"v"(w[22]),[w23]"v"(w[23]),
              [w24]"v"(w[24]),[w25]"v"(w[25]),[w26]"v"(w[26]),[w27]"v"(w[27]),
              [w28]"v"(w[28]),[w29]"v"(w[29]),[w30]"v"(w[30]),[w31]"v"(w[31]),
              [uv]"v"(uv), [bv]"v"(bv),
              [vRD]"v"(vRD), [vWR]"v"(vWR), [vXOR]"v"(vXOR),
              [vSX]"v"(vSX), [vA]"v"(vA), [vB]"v"(vB)
            : "memory",
              "v80","v81","v82","v83","v84","v85","v86","v87","v88","v89",
              "v90","v91","v92","v93","v94","v95","v96","v97","v98","v99",
              "v100","v101","v102","v103","v104","v105","v106","v107","v108");
    }

    // half1's h reg is garbage; the authoritative h is in the LDS row.
    const float hf = Hrow[k];
    float v = hf * W_head[k];
#pragma unroll
    for (int off = 16; off >= 1; off >>= 1)
        v += __shfl_xor(v, off, 32);
    if (lane == 0) out[b] = v + b_head[0];
}

extern "C" void kernel_launch(void* const* d_in, const int* in_sizes, int n_in,
                              void* d_out, int out_size, void* d_ws, size_t ws_size,
                              hipStream_t stream) {
    const float* x      = (const float*)d_in[0];
    const float* W_ih   = (const float*)d_in[1];
    const float* W_hh   = (const float*)d_in[2];
    const float* b_ih   = (const float*)d_in[3];
    const float* b_hh   = (const float*)d_in[4];
    const float* W_head = (const float*)d_in[5];
    const float* b_head = (const float*)d_in[6];
    float* out = (float*)d_out;

    const int B = in_sizes[0] / SEQ;              // 4096
    const int grid = B / WAVES_PER_BLOCK;         // 1024 blocks (4 waves each)

    lstm_fused_kernel<<<grid, BLOCK, 0, stream>>>(
        x, W_ih, W_hh, b_ih, b_hh, W_head, b_head, out);
}